// Round 10
// baseline (214.893 us; speedup 1.0000x reference)
//
#include <hip/hip_runtime.h>
#include <hip/hip_cooperative_groups.h>

// SpatialTransformer 2D->2D bilinear sampling — cooperative fused kernel with
// occupancy-sized grid and a hard fallback to the proven 3-node chain.
// Fused phases: (0) zero counters | grid.sync | (1) capacity-binned scatter
// (first bin's LDS tile prefetch issued before phase 1) | grid.sync |
// (2) per-block loop over its XCD-contiguous bins: stage 3x6-cell halo (36 KB)
// into LDS via global_load_lds, serve 4-corner gathers from LDS, nontemporal
// 2KB/point stores. Overflow points via direct global gather.

namespace cg = cooperative_groups;

typedef float f32x4 __attribute__((ext_vector_type(4)));

#define GLOBAL_AS __attribute__((address_space(1)))
#define LDS_AS    __attribute__((address_space(3)))

constexpr int NR   = 4;
constexpr int FH   = 90;
constexpr int FW   = 160;
constexpr int FDIM = 512;
constexpr int NV   = 120 * 160;    // 19200
constexpr int NPTS = NR * NV;      // 76800
constexpr int C4   = FDIM / 4;     // 128

constexpr int BY   = 2;
constexpr int BX   = 5;
constexpr int NGY  = FH / BY;      // 45
constexpr int NGX  = FW / BX;      // 32
constexpr int NBINS = NR * NGY * NGX;  // 5760
constexpr int NBX  = NBINS / 8;    // 720 bins per XCD slice
constexpr int SY   = BY + 1;       // 3
constexpr int SX   = BX + 1;       // 6
constexpr int SCELLS = SY * SX;    // 18 cells -> 36 KB
constexpr int LDSX4 = SCELLS * C4; // 2304 f32x4

constexpr int CAP   = 32;          // per-bin capacity (lambda = 13.3)
constexpr int OVCAP = 4096;
constexpr int TPB   = 512;

__device__ __forceinline__ f32x4 lerp4(f32x4 A, f32x4 B, f32x4 C, f32x4 D,
                                       float wa, float wb, float wc, float wd) {
    return wa * A + wb * B + wc * C + wd * D;
}

__device__ __forceinline__ void weights_and_cells(float x, float y,
                                                  int& x0, int& x1, int& y0, int& y1,
                                                  float& wa, float& wb, float& wc, float& wd) {
    float x0f = floorf(x), y0f = floorf(y);
    x0 = (int)x0f; y0 = (int)y0f;
    x1 = min(x0 + 1, FW - 1);
    y1 = min(y0 + 1, FH - 1);
    float wx1 = (float)x1 - x;
    float wx0 = x - x0f;
    float wy1 = (float)y1 - y;
    float wy0 = y - y0f;
    wa = wx1 * wy1; wb = wx1 * wy0; wc = wx0 * wy1; wd = wx0 * wy0;
}

__device__ __forceinline__ void stage_bin_dev(const f32x4* __restrict__ in4,
                                              f32x4* ldsbuf, int b, int tid) {
    int r   = b / (NGY * NGX);
    int by0 = (b / NGX % NGY) * BY;
    int bx0 = (b % NGX) * BX;
    #pragma unroll
    for (int i = 0; i < 5; ++i) {          // 2304 = 4.5 x 512; iter 4 guard is
        int idx = tid + i * TPB;           // wave-uniform (tid < 256)
        if (idx < LDSX4) {
            int cell = idx >> 7;
            int cc   = idx & (C4 - 1);
            int ry   = cell / SX;
            int rx   = cell - ry * SX;
            int gy   = min(by0 + ry, FH - 1);
            int gx   = min(bx0 + rx, FW - 1);
            __builtin_amdgcn_global_load_lds(
                (const GLOBAL_AS void*)(in4 + (size_t)((r * FH + gy) * FW + gx) * C4 + cc),
                (LDS_AS void*)&ldsbuf[idx], 16, 0, 0);
        }
    }
}

__global__ __launch_bounds__(TPB) void st_fused(
    const float* __restrict__ inp,
    const float* __restrict__ imx,
    const float* __restrict__ imy,
    int* __restrict__ binCnt,
    int* __restrict__ ovCnt,
    int* __restrict__ perm,
    float2* __restrict__ sXY,
    int* __restrict__ ovList,
    float* __restrict__ out)
{
    __shared__ f32x4  lds[LDSX4];    // 36 KB halo tile
    __shared__ int    pmS[CAP];
    __shared__ float2 xyS[CAP];

    cg::grid_group grid = cg::this_grid();
    int nblk = gridDim.x;                 // multiple of 8 (host guarantees)
    int nthreads = nblk * TPB;
    int bid = blockIdx.x;
    int tid = threadIdx.x;
    int gt  = bid * TPB + tid;

    const f32x4* in4 = (const f32x4*)inp;

    // Block's bin range: XCD-chunked (blocks with equal bid&7 share an XCD
    // under round-robin dispatch and cover a contiguous slice of that XCD's
    // 720 bins).
    int xcd = bid & 7;
    int s   = bid >> 3;
    int bpx = nblk >> 3;
    int s0  = (s * NBX) / bpx;
    int s1  = ((s + 1) * NBX) / bpx;

    // ---- Phase 0: zero counters ----
    for (int i = gt; i < NBINS + 1; i += nthreads) binCnt[i] = 0;
    __threadfence();
    grid.sync();

    // Prefetch first owned bin's tile; latency hides under phase 1 + sync.
    stage_bin_dev(in4, lds, xcd * NBX + s0, tid);

    // ---- Phase 1: capacity-binned scatter ----
    for (int pt = gt; pt < NPTS; pt += nthreads) {
        int r = pt / NV;
        float x = fminf(fmaxf(imx[pt], 0.0f), (float)(FW - 1));
        float y = fminf(fmaxf(imy[pt], 0.0f), (float)(FH - 1));
        int b = (r * NGY + (int)floorf(y) / BY) * NGX + (int)floorf(x) / BX;
        int slot = atomicAdd(&binCnt[b], 1);
        if (slot < CAP) {
            int idx = b * CAP + slot;
            perm[idx] = pt;
            sXY[idx] = make_float2(x, y);
        } else {
            int o = atomicAdd(ovCnt, 1);
            if (o < OVCAP) ovList[o] = pt;
        }
    }
    __threadfence();
    grid.sync();

    // ---- Phase 2: bin processing ----
    f32x4* out4 = (f32x4*)out;
    int g  = tid >> 7;            // 4 groups of 128 threads
    int c4 = tid & (C4 - 1);

    for (int k = s0; k < s1; ++k) {
        int b = xcd * NBX + k;
        if (k > s0)
            stage_bin_dev(in4, lds, b, tid);   // first bin pre-staged above

        int by0 = (b / NGX % NGY) * BY;
        int bx0 = (b % NGX) * BX;
        int cnt  = min(binCnt[b], CAP);
        int base = b * CAP;
        if (tid < cnt) {
            pmS[tid] = perm[base + tid];
            xyS[tid] = sXY[base + tid];
        }
        __syncthreads();   // drains vmcnt(0): staged tile + meta visible

        int i = g;
        for (; i + 4 < cnt; i += 8) {
            int    ptA = pmS[i];
            float2 cA  = xyS[i];
            int    ptB = pmS[i + 4];
            float2 cB  = xyS[i + 4];

            int x0A, x1A, y0A, y1A, x0B, x1B, y0B, y1B;
            float waA, wbA, wcA, wdA, waB, wbB, wcB, wdB;
            weights_and_cells(cA.x, cA.y, x0A, x1A, y0A, y1A, waA, wbA, wcA, wdA);
            weights_and_cells(cB.x, cB.y, x0B, x1B, y0B, y1B, waB, wbB, wcB, wdB);

            f32x4 Aa = lds[(((y0A - by0) * SX + (x0A - bx0)) << 7) + c4];
            f32x4 Ab = lds[(((y1A - by0) * SX + (x0A - bx0)) << 7) + c4];
            f32x4 Ac = lds[(((y0A - by0) * SX + (x1A - bx0)) << 7) + c4];
            f32x4 Ad = lds[(((y1A - by0) * SX + (x1A - bx0)) << 7) + c4];
            f32x4 Ba = lds[(((y0B - by0) * SX + (x0B - bx0)) << 7) + c4];
            f32x4 Bb = lds[(((y1B - by0) * SX + (x0B - bx0)) << 7) + c4];
            f32x4 Bc = lds[(((y0B - by0) * SX + (x1B - bx0)) << 7) + c4];
            f32x4 Bd = lds[(((y1B - by0) * SX + (x1B - bx0)) << 7) + c4];

            __builtin_nontemporal_store(lerp4(Aa, Ab, Ac, Ad, waA, wbA, wcA, wdA),
                                        out4 + (size_t)ptA * C4 + c4);
            __builtin_nontemporal_store(lerp4(Ba, Bb, Bc, Bd, waB, wbB, wcB, wdB),
                                        out4 + (size_t)ptB * C4 + c4);
        }
        if (i < cnt) {
            int    pt = pmS[i];
            float2 cc = xyS[i];
            int x0, x1, y0, y1; float wa, wb, wc, wd;
            weights_and_cells(cc.x, cc.y, x0, x1, y0, y1, wa, wb, wc, wd);
            f32x4 A = lds[(((y0 - by0) * SX + (x0 - bx0)) << 7) + c4];
            f32x4 B = lds[(((y1 - by0) * SX + (x0 - bx0)) << 7) + c4];
            f32x4 C = lds[(((y0 - by0) * SX + (x1 - bx0)) << 7) + c4];
            f32x4 D = lds[(((y1 - by0) * SX + (x1 - bx0)) << 7) + c4];
            __builtin_nontemporal_store(lerp4(A, B, C, D, wa, wb, wc, wd),
                                        out4 + (size_t)pt * C4 + c4);
        }
        __syncthreads();   // lds reads done before next bin's stage overwrites
    }

    // Cold path: overflow points (slot >= CAP) via direct global gather.
    int ov = min(*ovCnt, OVCAP);
    for (int j = bid; j < ov; j += nblk) {
        if (g != 0) continue;
        int pt = ovList[j];
        int rr = pt / NV;
        float x = fminf(fmaxf(imx[pt], 0.0f), (float)(FW - 1));
        float y = fminf(fmaxf(imy[pt], 0.0f), (float)(FH - 1));
        int x0, x1, y0, y1; float wa, wb, wc, wd;
        weights_and_cells(x, y, x0, x1, y0, y1, wa, wb, wc, wd);
        int rb = rr * FH;
        f32x4 A = in4[(size_t)((rb + y0) * FW + x0) * C4 + c4];
        f32x4 B = in4[(size_t)((rb + y1) * FW + x0) * C4 + c4];
        f32x4 C = in4[(size_t)((rb + y0) * FW + x1) * C4 + c4];
        f32x4 D = in4[(size_t)((rb + y1) * FW + x1) * C4 + c4];
        __builtin_nontemporal_store(lerp4(A, B, C, D, wa, wb, wc, wd),
                                    out4 + (size_t)pt * C4 + c4);
    }
}

// ---- Fallback chain (proven R7 path) ----

__global__ void k_scatter(const float* __restrict__ imx, const float* __restrict__ imy,
                          int* __restrict__ binCnt, int* __restrict__ ovCnt,
                          int* __restrict__ perm, float2* __restrict__ sXY,
                          int* __restrict__ ovList) {
    int pt = blockIdx.x * blockDim.x + threadIdx.x;
    if (pt >= NPTS) return;
    int r = pt / NV;
    float x = fminf(fmaxf(imx[pt], 0.0f), (float)(FW - 1));
    float y = fminf(fmaxf(imy[pt], 0.0f), (float)(FH - 1));
    int b = (r * NGY + (int)floorf(y) / BY) * NGX + (int)floorf(x) / BX;
    int slot = atomicAdd(&binCnt[b], 1);
    if (slot < CAP) {
        int idx = b * CAP + slot;
        perm[idx] = pt;
        sXY[idx] = make_float2(x, y);
    } else {
        int o = atomicAdd(ovCnt, 1);
        if (o < OVCAP) ovList[o] = pt;
    }
}

__global__ __launch_bounds__(TPB) void st_bins(
    const float* __restrict__ inp,
    const int* __restrict__ binCnt,
    const int* __restrict__ ovCnt,
    const int* __restrict__ perm,
    const float2* __restrict__ sXY,
    const int* __restrict__ ovList,
    const float* __restrict__ imx,
    const float* __restrict__ imy,
    float* __restrict__ out)
{
    __shared__ f32x4  lds[LDSX4];
    __shared__ int    pmS[CAP];
    __shared__ float2 xyS[CAP];

    int p = blockIdx.x;
    int b = (p & 7) * (NBINS >> 3) + (p >> 3);

    int by0 = (b / NGX % NGY) * BY;
    int bx0 = (b % NGX) * BX;
    int tid = threadIdx.x;

    const f32x4* in4 = (const f32x4*)inp;
    int cnt  = min(binCnt[b], CAP);
    int base = b * CAP;

    stage_bin_dev(in4, lds, b, tid);
    if (tid < cnt) {
        pmS[tid] = perm[base + tid];
        xyS[tid] = sXY[base + tid];
    }
    __syncthreads();

    int g  = tid >> 7;
    int c4 = tid & (C4 - 1);
    f32x4* out4 = (f32x4*)out;

    int i = g;
    for (; i + 4 < cnt; i += 8) {
        int    ptA = pmS[i];
        float2 cA  = xyS[i];
        int    ptB = pmS[i + 4];
        float2 cB  = xyS[i + 4];

        int x0A, x1A, y0A, y1A, x0B, x1B, y0B, y1B;
        float waA, wbA, wcA, wdA, waB, wbB, wcB, wdB;
        weights_and_cells(cA.x, cA.y, x0A, x1A, y0A, y1A, waA, wbA, wcA, wdA);
        weights_and_cells(cB.x, cB.y, x0B, x1B, y0B, y1B, waB, wbB, wcB, wdB);

        f32x4 Aa = lds[(((y0A - by0) * SX + (x0A - bx0)) << 7) + c4];
        f32x4 Ab = lds[(((y1A - by0) * SX + (x0A - bx0)) << 7) + c4];
        f32x4 Ac = lds[(((y0A - by0) * SX + (x1A - bx0)) << 7) + c4];
        f32x4 Ad = lds[(((y1A - by0) * SX + (x1A - bx0)) << 7) + c4];
        f32x4 Ba = lds[(((y0B - by0) * SX + (x0B - bx0)) << 7) + c4];
        f32x4 Bb = lds[(((y1B - by0) * SX + (x0B - bx0)) << 7) + c4];
        f32x4 Bc = lds[(((y0B - by0) * SX + (x1B - bx0)) << 7) + c4];
        f32x4 Bd = lds[(((y1B - by0) * SX + (x1B - bx0)) << 7) + c4];

        __builtin_nontemporal_store(lerp4(Aa, Ab, Ac, Ad, waA, wbA, wcA, wdA),
                                    out4 + (size_t)ptA * C4 + c4);
        __builtin_nontemporal_store(lerp4(Ba, Bb, Bc, Bd, waB, wbB, wcB, wdB),
                                    out4 + (size_t)ptB * C4 + c4);
    }
    if (i < cnt) {
        int    pt = pmS[i];
        float2 cc = xyS[i];
        int x0, x1, y0, y1; float wa, wb, wc, wd;
        weights_and_cells(cc.x, cc.y, x0, x1, y0, y1, wa, wb, wc, wd);
        f32x4 A = lds[(((y0 - by0) * SX + (x0 - bx0)) << 7) + c4];
        f32x4 B = lds[(((y1 - by0) * SX + (x0 - bx0)) << 7) + c4];
        f32x4 C = lds[(((y0 - by0) * SX + (x1 - bx0)) << 7) + c4];
        f32x4 D = lds[(((y1 - by0) * SX + (x1 - bx0)) << 7) + c4];
        __builtin_nontemporal_store(lerp4(A, B, C, D, wa, wb, wc, wd),
                                    out4 + (size_t)pt * C4 + c4);
    }

    int ov = min(*ovCnt, OVCAP);
    for (int j = b; j < ov; j += NBINS) {
        if (g != 0) continue;
        int pt = ovList[j];
        int rr = pt / NV;
        float x = fminf(fmaxf(imx[pt], 0.0f), (float)(FW - 1));
        float y = fminf(fmaxf(imy[pt], 0.0f), (float)(FH - 1));
        int x0, x1, y0, y1; float wa, wb, wc, wd;
        weights_and_cells(x, y, x0, x1, y0, y1, wa, wb, wc, wd);
        int rb = rr * FH;
        f32x4 A = in4[(size_t)((rb + y0) * FW + x0) * C4 + c4];
        f32x4 B = in4[(size_t)((rb + y1) * FW + x0) * C4 + c4];
        f32x4 C = in4[(size_t)((rb + y0) * FW + x1) * C4 + c4];
        f32x4 D = in4[(size_t)((rb + y1) * FW + x1) * C4 + c4];
        __builtin_nontemporal_store(lerp4(A, B, C, D, wa, wb, wc, wd),
                                    out4 + (size_t)pt * C4 + c4);
    }
}

__global__ __launch_bounds__(256) void st_bilinear_direct(
    const float* __restrict__ inp,
    const float* __restrict__ imx,
    const float* __restrict__ imy,
    float* __restrict__ out)
{
    int gid = blockIdx.x * blockDim.x + threadIdx.x;
    int pt = gid >> 7;
    int c4 = gid & (C4 - 1);
    if (pt >= NPTS) return;
    int r = pt / NV;
    float x = fminf(fmaxf(imx[pt], 0.0f), (float)(FW - 1));
    float y = fminf(fmaxf(imy[pt], 0.0f), (float)(FH - 1));
    int x0, x1, y0, y1; float wa, wb, wc, wd;
    weights_and_cells(x, y, x0, x1, y0, y1, wa, wb, wc, wd);
    const f32x4* base = (const f32x4*)inp;
    int rb = r * FH;
    f32x4 a = base[(size_t)((rb + y0) * FW + x0) * C4 + c4];
    f32x4 b = base[(size_t)((rb + y1) * FW + x0) * C4 + c4];
    f32x4 c = base[(size_t)((rb + y0) * FW + x1) * C4 + c4];
    f32x4 d = base[(size_t)((rb + y1) * FW + x1) * C4 + c4];
    ((f32x4*)out)[(size_t)pt * C4 + c4] = lerp4(a, b, c, d, wa, wb, wc, wd);
}

extern "C" void kernel_launch(void* const* d_in, const int* in_sizes, int n_in,
                              void* d_out, int out_size, void* d_ws, size_t ws_size,
                              hipStream_t stream) {
    const float* inp = (const float*)d_in[0];
    const float* imx = (const float*)d_in[1];
    const float* imy = (const float*)d_in[2];
    float* out = (float*)d_out;

    // ws layout (aligned): sXY[NBINS*CAP] float2 | perm[NBINS*CAP] | binCnt | ovCnt | ovList
    size_t need = (size_t)NBINS * CAP * sizeof(float2)
                + (size_t)(NBINS * CAP + NBINS + 1 + OVCAP) * sizeof(int);

    if (ws_size < need) {
        int nblocks = (NPTS * C4) / 256;
        hipLaunchKernelGGL(st_bilinear_direct, dim3(nblocks), dim3(256), 0, stream,
                           inp, imx, imy, out);
        return;
    }

    float2* sXY    = (float2*)d_ws;
    int*    perm   = (int*)(sXY + (size_t)NBINS * CAP);
    int*    binCnt = perm + (size_t)NBINS * CAP;
    int*    ovCnt  = binCnt + NBINS;
    int*    ovList = ovCnt + 1;

    // Cooperative path: grid sized by QUERIED occupancy, launch return checked.
    int dev = 0, coop = 0, ncu = 0, bpc = 0;
    (void)hipGetDevice(&dev);
    (void)hipDeviceGetAttribute(&coop, hipDeviceAttributeCooperativeLaunch, dev);
    (void)hipDeviceGetAttribute(&ncu, hipDeviceAttributeMultiprocessorCount, dev);
    hipError_t oe = hipOccupancyMaxActiveBlocksPerMultiprocessor(
        &bpc, (const void*)st_fused, TPB, 0);

    if (coop && oe == hipSuccess && ncu > 0 && bpc > 0) {
        int nblk = (ncu * bpc) & ~7;       // multiple of 8 for XCD math
        if (nblk > 1024) nblk = 1024;
        if (nblk >= 8) {
            void* args[] = { (void*)&inp, (void*)&imx, (void*)&imy,
                             (void*)&binCnt, (void*)&ovCnt, (void*)&perm,
                             (void*)&sXY, (void*)&ovList, (void*)&out };
            hipError_t le = hipLaunchCooperativeKernel(
                (const void*)st_fused, dim3(nblk), dim3(TPB), args, 0, stream);
            if (le == hipSuccess) return;
        }
    }

    // Fallback: proven 3-node chain (memset -> scatter -> st_bins).
    (void)hipMemsetAsync(binCnt, 0, (NBINS + 1) * sizeof(int), stream);
    hipLaunchKernelGGL(k_scatter, dim3((NPTS + 255) / 256), dim3(256), 0, stream,
                       imx, imy, binCnt, ovCnt, perm, sXY, ovList);
    hipLaunchKernelGGL(st_bins, dim3(NBINS), dim3(TPB), 0, stream,
                       inp, binCnt, ovCnt, perm, sXY, ovList, imx, imy, out);
}

// Round 11
// 60.497 us; speedup vs baseline: 3.5521x; 3.5521x over previous
//
#include <hip/hip_runtime.h>

// SpatialTransformer 2D->2D bilinear sampling.
// Pipeline (3 graph nodes):
//   hipMemsetAsync : zero binCnt[NBINS]+ovCnt
//   k_scatter      : single-pass capacity-binned scatter; pre-gathers clamped
//                    (x,y) float2 into bin-sorted order
//   st_bins_half   : TWO blocks per (view, 2x5-cell) bin, split by channel
//                    half. Each block stages its 64-chunk half of the 3x6-cell
//                    halo (18 KB) via global_load_lds (1 wave = 1 cell-half,
//                    perfectly linear), serves 4-corner gathers from LDS,
//                    nontemporal 1KB/wave stores. 256 thr/block ->
//                    8 blocks/CU = 32 waves/CU with 8 independent
//                    stage/compute units per CU (vs 4 in the monolithic
//                    version) for better stage-latency hiding.

typedef float f32x4 __attribute__((ext_vector_type(4)));

#define GLOBAL_AS __attribute__((address_space(1)))
#define LDS_AS    __attribute__((address_space(3)))

constexpr int NR   = 4;
constexpr int FH   = 90;
constexpr int FW   = 160;
constexpr int FDIM = 512;
constexpr int NV   = 120 * 160;    // 19200
constexpr int NPTS = NR * NV;      // 76800
constexpr int C4   = FDIM / 4;     // 128 chunks per point
constexpr int H4   = C4 / 2;       // 64 chunks per half

constexpr int BY   = 2;
constexpr int BX   = 5;
constexpr int NGY  = FH / BY;      // 45
constexpr int NGX  = FW / BX;      // 32
constexpr int NBINS = NR * NGY * NGX;  // 5760
constexpr int NB2  = NBINS * 2;    // 11520 blocks (2 halves per bin)
constexpr int SY   = BY + 1;       // 3
constexpr int SX   = BX + 1;       // 6
constexpr int SCELLS = SY * SX;    // 18 cells
constexpr int LDSH = SCELLS * H4;  // 1152 f32x4 = 18 KB per half

constexpr int CAP   = 32;          // per-bin capacity (lambda = 13.3)
constexpr int OVCAP = 4096;
constexpr int TPB   = 256;

__global__ void k_scatter(const float* __restrict__ imx, const float* __restrict__ imy,
                          int* __restrict__ binCnt, int* __restrict__ ovCnt,
                          int* __restrict__ perm, float2* __restrict__ sXY,
                          int* __restrict__ ovList) {
    int pt = blockIdx.x * blockDim.x + threadIdx.x;
    if (pt >= NPTS) return;
    int r = pt / NV;
    float x = fminf(fmaxf(imx[pt], 0.0f), (float)(FW - 1));
    float y = fminf(fmaxf(imy[pt], 0.0f), (float)(FH - 1));
    int b = (r * NGY + (int)floorf(y) / BY) * NGX + (int)floorf(x) / BX;
    int slot = atomicAdd(&binCnt[b], 1);
    if (slot < CAP) {
        int idx = b * CAP + slot;
        perm[idx] = pt;
        sXY[idx] = make_float2(x, y);
    } else {
        int o = atomicAdd(ovCnt, 1);
        if (o < OVCAP) ovList[o] = pt;
    }
}

__device__ __forceinline__ f32x4 lerp4(f32x4 A, f32x4 B, f32x4 C, f32x4 D,
                                       float wa, float wb, float wc, float wd) {
    return wa * A + wb * B + wc * C + wd * D;
}

__device__ __forceinline__ void weights_and_cells(float x, float y,
                                                  int& x0, int& x1, int& y0, int& y1,
                                                  float& wa, float& wb, float& wc, float& wd) {
    float x0f = floorf(x), y0f = floorf(y);
    x0 = (int)x0f; y0 = (int)y0f;
    x1 = min(x0 + 1, FW - 1);
    y1 = min(y0 + 1, FH - 1);
    float wx1 = (float)x1 - x;
    float wx0 = x - x0f;
    float wy1 = (float)y1 - y;
    float wy0 = y - y0f;
    wa = wx1 * wy1; wb = wx1 * wy0; wc = wx0 * wy1; wd = wx0 * wy0;
}

__global__ __launch_bounds__(TPB) void st_bins_half(
    const float* __restrict__ inp,
    const int* __restrict__ binCnt,
    const int* __restrict__ ovCnt,
    const int* __restrict__ perm,
    const float2* __restrict__ sXY,
    const int* __restrict__ ovList,
    float* __restrict__ out)
{
    __shared__ f32x4  lds[LDSH];     // 18 KB: this half's chunks of the halo
    __shared__ int    pmS[CAP];
    __shared__ float2 xyS[CAP];

    int p = blockIdx.x;
    // Chunked XCD swizzle over the 11520 block ids; consecutive l = both
    // halves of the same bin -> same XCD slice covers contiguous bins.
    int l    = (p & 7) * (NB2 >> 3) + (p >> 3);
    int b    = l >> 1;
    int half = l & 1;

    int r   = b / (NGY * NGX);
    int by0 = (b / NGX % NGY) * BY;
    int bx0 = (b % NGX) * BX;
    int tid = threadIdx.x;

    const f32x4* in4 = (const f32x4*)inp;
    int cnt  = min(binCnt[b], CAP);
    int base = b * CAP;
    int hofs = half * H4;

    // Async staging: 1152 f32x4 = 4.5 x 256 threads. One wave covers exactly
    // one cell-half: LDS dest = wave-uniform base + lane*16, global source
    // 1 KB contiguous. Iteration 4's guard (tid < 128) is wave-uniform.
    #pragma unroll
    for (int i = 0; i < 5; ++i) {
        int idx = tid + i * TPB;
        if (idx < LDSH) {
            int cell = idx >> 6;           // 64 chunks per cell-half
            int cc   = idx & (H4 - 1);
            int ry   = cell / SX;
            int rx   = cell - ry * SX;
            int gy   = min(by0 + ry, FH - 1);
            int gx   = min(bx0 + rx, FW - 1);
            __builtin_amdgcn_global_load_lds(
                (const GLOBAL_AS void*)(in4 + (size_t)((r * FH + gy) * FW + gx) * C4 + hofs + cc),
                (LDS_AS void*)&lds[idx], 16, 0, 0);
        }
    }
    // Stage point metadata (overlaps with async tile staging).
    if (tid < cnt) {
        pmS[tid] = perm[base + tid];
        xyS[tid] = sXY[base + tid];
    }
    __syncthreads();   // drains vmcnt(0): staged tile + meta visible

    int g  = tid >> 6;            // 4 groups = 4 waves; 1 wave per point
    int cc = tid & (H4 - 1);
    f32x4* out4 = (f32x4*)out;

    int i = g;
    // 2-point unrolled loop per wave: 8 LDS reads in flight.
    for (; i + 4 < cnt; i += 8) {
        int    ptA = pmS[i];
        float2 cA  = xyS[i];
        int    ptB = pmS[i + 4];
        float2 cB  = xyS[i + 4];

        int x0A, x1A, y0A, y1A, x0B, x1B, y0B, y1B;
        float waA, wbA, wcA, wdA, waB, wbB, wcB, wdB;
        weights_and_cells(cA.x, cA.y, x0A, x1A, y0A, y1A, waA, wbA, wcA, wdA);
        weights_and_cells(cB.x, cB.y, x0B, x1B, y0B, y1B, waB, wbB, wcB, wdB);

        f32x4 Aa = lds[(((y0A - by0) * SX + (x0A - bx0)) << 6) + cc];
        f32x4 Ab = lds[(((y1A - by0) * SX + (x0A - bx0)) << 6) + cc];
        f32x4 Ac = lds[(((y0A - by0) * SX + (x1A - bx0)) << 6) + cc];
        f32x4 Ad = lds[(((y1A - by0) * SX + (x1A - bx0)) << 6) + cc];
        f32x4 Ba = lds[(((y0B - by0) * SX + (x0B - bx0)) << 6) + cc];
        f32x4 Bb = lds[(((y1B - by0) * SX + (x0B - bx0)) << 6) + cc];
        f32x4 Bc = lds[(((y0B - by0) * SX + (x1B - bx0)) << 6) + cc];
        f32x4 Bd = lds[(((y1B - by0) * SX + (x1B - bx0)) << 6) + cc];

        __builtin_nontemporal_store(lerp4(Aa, Ab, Ac, Ad, waA, wbA, wcA, wdA),
                                    out4 + (size_t)ptA * C4 + hofs + cc);
        __builtin_nontemporal_store(lerp4(Ba, Bb, Bc, Bd, waB, wbB, wcB, wdB),
                                    out4 + (size_t)ptB * C4 + hofs + cc);
    }
    if (i < cnt) {
        int    pt = pmS[i];
        float2 cx = xyS[i];
        int x0, x1, y0, y1; float wa, wb, wc, wd;
        weights_and_cells(cx.x, cx.y, x0, x1, y0, y1, wa, wb, wc, wd);
        f32x4 A = lds[(((y0 - by0) * SX + (x0 - bx0)) << 6) + cc];
        f32x4 B = lds[(((y1 - by0) * SX + (x0 - bx0)) << 6) + cc];
        f32x4 C = lds[(((y0 - by0) * SX + (x1 - bx0)) << 6) + cc];
        f32x4 D = lds[(((y1 - by0) * SX + (x1 - bx0)) << 6) + cc];
        __builtin_nontemporal_store(lerp4(A, B, C, D, wa, wb, wc, wd),
                                    out4 + (size_t)pt * C4 + hofs + cc);
    }

    // Cold path: overflow points; blocks 2j and 2j+1 each write their half.
    int ov = min(*ovCnt, OVCAP);
    const f32x4* basep = in4;
    for (int j = l >> 1; j < ov; j += NB2 >> 1) {
        if (g != 0 || (l & 1) != half) continue;   // group 0 only
        int pt = ovList[j];
        int rr = pt / NV;
        // Recompute clamped coords from the bin-independent formula is not
        // possible here (imx/imy not passed); use sXY path instead: overflow
        // points were never stored, so gather coords from perm? They aren't
        // there either — handled below via direct recompute kernel-side.
        // NOTE: coords for overflow points are recomputed in k_scatter's
        // formula using the ovList payload: we store pt only, so we must
        // re-read imx/imy. Pass-through pointers kept in launcher ensure
        // this path is never needed for uniform inputs (ov == 0).
        (void)pt; (void)rr; (void)basep;
    }
}

// Overflow finisher: direct global gather for slot>=CAP points (ov ~ 0 for
// uniform coords; separate tiny kernel keeps the hot kernel's reg/LDS lean).
__global__ __launch_bounds__(TPB) void st_overflow(
    const float* __restrict__ inp,
    const float* __restrict__ imx,
    const float* __restrict__ imy,
    const int* __restrict__ ovCnt,
    const int* __restrict__ ovList,
    float* __restrict__ out)
{
    int ov = min(*ovCnt, OVCAP);
    // 2 points per block (128 threads each).
    int slot = blockIdx.x * 2 + (threadIdx.x >> 7);
    if (slot >= ov) return;
    int c4 = threadIdx.x & (C4 - 1);
    int pt = ovList[slot];
    int r = pt / NV;
    float x = fminf(fmaxf(imx[pt], 0.0f), (float)(FW - 1));
    float y = fminf(fmaxf(imy[pt], 0.0f), (float)(FH - 1));
    int x0, x1, y0, y1; float wa, wb, wc, wd;
    weights_and_cells(x, y, x0, x1, y0, y1, wa, wb, wc, wd);
    const f32x4* in4 = (const f32x4*)inp;
    int rb = r * FH;
    f32x4 A = in4[(size_t)((rb + y0) * FW + x0) * C4 + c4];
    f32x4 B = in4[(size_t)((rb + y1) * FW + x0) * C4 + c4];
    f32x4 C = in4[(size_t)((rb + y0) * FW + x1) * C4 + c4];
    f32x4 D = in4[(size_t)((rb + y1) * FW + x1) * C4 + c4];
    ((f32x4*)out)[(size_t)pt * C4 + c4] = lerp4(A, B, C, D, wa, wb, wc, wd);
}

// Fallback (workspace too small): unsorted direct kernel.
__global__ __launch_bounds__(256) void st_bilinear_direct(
    const float* __restrict__ inp,
    const float* __restrict__ imx,
    const float* __restrict__ imy,
    float* __restrict__ out)
{
    int gid = blockIdx.x * blockDim.x + threadIdx.x;
    int pt = gid >> 7;
    int c4 = gid & (C4 - 1);
    if (pt >= NPTS) return;
    int r = pt / NV;
    float x = fminf(fmaxf(imx[pt], 0.0f), (float)(FW - 1));
    float y = fminf(fmaxf(imy[pt], 0.0f), (float)(FH - 1));
    int x0, x1, y0, y1; float wa, wb, wc, wd;
    weights_and_cells(x, y, x0, x1, y0, y1, wa, wb, wc, wd);
    const f32x4* base = (const f32x4*)inp;
    int rb = r * FH;
    f32x4 a = base[(size_t)((rb + y0) * FW + x0) * C4 + c4];
    f32x4 b = base[(size_t)((rb + y1) * FW + x0) * C4 + c4];
    f32x4 c = base[(size_t)((rb + y0) * FW + x1) * C4 + c4];
    f32x4 d = base[(size_t)((rb + y1) * FW + x1) * C4 + c4];
    ((f32x4*)out)[(size_t)pt * C4 + c4] = lerp4(a, b, c, d, wa, wb, wc, wd);
}

extern "C" void kernel_launch(void* const* d_in, const int* in_sizes, int n_in,
                              void* d_out, int out_size, void* d_ws, size_t ws_size,
                              hipStream_t stream) {
    const float* inp = (const float*)d_in[0];
    const float* imx = (const float*)d_in[1];
    const float* imy = (const float*)d_in[2];
    float* out = (float*)d_out;

    // ws layout (aligned): sXY[NBINS*CAP] float2 | perm | binCnt | ovCnt | ovList
    size_t need = (size_t)NBINS * CAP * sizeof(float2)
                + (size_t)(NBINS * CAP + NBINS + 1 + OVCAP) * sizeof(int);

    if (ws_size < need) {
        int nblocks = (NPTS * C4) / 256;
        hipLaunchKernelGGL(st_bilinear_direct, dim3(nblocks), dim3(256), 0, stream,
                           inp, imx, imy, out);
        return;
    }

    float2* sXY    = (float2*)d_ws;
    int*    perm   = (int*)(sXY + (size_t)NBINS * CAP);
    int*    binCnt = perm + (size_t)NBINS * CAP;
    int*    ovCnt  = binCnt + NBINS;
    int*    ovList = ovCnt + 1;

    (void)hipMemsetAsync(binCnt, 0, (NBINS + 1) * sizeof(int), stream);
    hipLaunchKernelGGL(k_scatter, dim3((NPTS + 255) / 256), dim3(256), 0, stream,
                       imx, imy, binCnt, ovCnt, perm, sXY, ovList);
    hipLaunchKernelGGL(st_bins_half, dim3(NB2), dim3(TPB), 0, stream,
                       inp, binCnt, ovCnt, perm, sXY, ovList, out);
    // Overflow finisher (ov == 0 for the benchmark's uniform coords; the
    // kernel exits immediately in that case). Grid sized for worst case.
    hipLaunchKernelGGL(st_overflow, dim3(OVCAP / 2), dim3(TPB), 0, stream,
                       inp, imx, imy, ovCnt, ovList, out);
}

// Round 12
// 58.575 us; speedup vs baseline: 3.6687x; 1.0328x over previous
//
#include <hip/hip_runtime.h>

// SpatialTransformer 2D->2D bilinear sampling.  [FINAL: proven R7 config]
// Pipeline (3 graph nodes):
//   hipMemsetAsync : zero binCnt[NBINS]+ovCnt
//   k_scatter      : single-pass capacity-binned scatter; pre-gathers clamped
//                    (x,y) float2 into bin-sorted order
//   st_bins        : one 512-thread block per (view, 2x5-cell) bin; stages the
//                    3x6-cell halo footprint (36 KB) into LDS via async
//                    global_load_lds -> 4 blocks/CU = 32 waves/CU (max TLP).
//                    Serves all 4-corner gathers from LDS, nontemporal stores.
//                    Overflow points (slot>=CAP) via direct global gather.
// Measured: 58.6 us total; main kernel runs at the mixed read/write HBM
// limit (~215 MB at ~4.7 TB/s). Structural variants (double-buffer
// persistent, cooperative fusion, channel-half split) all regressed.

typedef float f32x4 __attribute__((ext_vector_type(4)));

#define GLOBAL_AS __attribute__((address_space(1)))
#define LDS_AS    __attribute__((address_space(3)))

constexpr int NR   = 4;
constexpr int FH   = 90;
constexpr int FW   = 160;
constexpr int FDIM = 512;
constexpr int NV   = 120 * 160;    // 19200
constexpr int NPTS = NR * NV;      // 76800
constexpr int C4   = FDIM / 4;     // 128

constexpr int BY   = 2;            // bin height in cells
constexpr int BX   = 5;            // bin width in cells
constexpr int NGY  = FH / BY;      // 45
constexpr int NGX  = FW / BX;      // 32
constexpr int NBINS = NR * NGY * NGX;  // 5760 (divisible by 8)
constexpr int SY   = BY + 1;       // 3 staged rows
constexpr int SX   = BX + 1;       // 6 staged cols
constexpr int SCELLS = SY * SX;    // 18 cells -> 36 KB LDS
constexpr int LDSX4 = SCELLS * C4; // 2304 f32x4

constexpr int CAP   = 32;          // per-bin capacity (lambda = 13.3)
constexpr int OVCAP = 4096;
constexpr int TPB   = 512;

__global__ void k_scatter(const float* __restrict__ imx, const float* __restrict__ imy,
                          int* __restrict__ binCnt, int* __restrict__ ovCnt,
                          int* __restrict__ perm, float2* __restrict__ sXY,
                          int* __restrict__ ovList) {
    int pt = blockIdx.x * blockDim.x + threadIdx.x;
    if (pt >= NPTS) return;
    int r = pt / NV;
    float x = fminf(fmaxf(imx[pt], 0.0f), (float)(FW - 1));
    float y = fminf(fmaxf(imy[pt], 0.0f), (float)(FH - 1));
    int b = (r * NGY + (int)floorf(y) / BY) * NGX + (int)floorf(x) / BX;
    int slot = atomicAdd(&binCnt[b], 1);
    if (slot < CAP) {
        int idx = b * CAP + slot;
        perm[idx] = pt;
        sXY[idx] = make_float2(x, y);
    } else {
        int o = atomicAdd(ovCnt, 1);
        if (o < OVCAP) ovList[o] = pt;
    }
}

__device__ __forceinline__ f32x4 lerp4(f32x4 A, f32x4 B, f32x4 C, f32x4 D,
                                       float wa, float wb, float wc, float wd) {
    return wa * A + wb * B + wc * C + wd * D;
}

__device__ __forceinline__ void weights_and_cells(float x, float y,
                                                  int& x0, int& x1, int& y0, int& y1,
                                                  float& wa, float& wb, float& wc, float& wd) {
    float x0f = floorf(x), y0f = floorf(y);
    x0 = (int)x0f; y0 = (int)y0f;
    x1 = min(x0 + 1, FW - 1);
    y1 = min(y0 + 1, FH - 1);
    float wx1 = (float)x1 - x;
    float wx0 = x - x0f;
    float wy1 = (float)y1 - y;
    float wy0 = y - y0f;
    wa = wx1 * wy1; wb = wx1 * wy0; wc = wx0 * wy1; wd = wx0 * wy0;
}

__global__ __launch_bounds__(TPB) void st_bins(
    const float* __restrict__ inp,
    const int* __restrict__ binCnt,
    const int* __restrict__ ovCnt,
    const int* __restrict__ perm,
    const float2* __restrict__ sXY,
    const int* __restrict__ ovList,
    const float* __restrict__ imx,
    const float* __restrict__ imy,
    float* __restrict__ out)
{
    __shared__ f32x4  lds[LDSX4];    // 36 KB halo tile
    __shared__ int    pmS[CAP];
    __shared__ float2 xyS[CAP];

    int p = blockIdx.x;
    int b = (p & 7) * (NBINS >> 3) + (p >> 3);   // chunked XCD swizzle

    int r   = b / (NGY * NGX);
    int by0 = (b / NGX % NGY) * BY;
    int bx0 = (b % NGX) * BX;
    int tid = threadIdx.x;

    const f32x4* in4 = (const f32x4*)inp;
    int cnt  = min(binCnt[b], CAP);
    int base = b * CAP;

    // Async staging: 2304 f32x4 = 4.5 x 512 threads; iteration 4's guard
    // (tid < 256) is wave-uniform (4 full waves active, 4 fully inactive).
    #pragma unroll
    for (int i = 0; i < 5; ++i) {
        int idx = tid + i * TPB;
        if (idx < LDSX4) {
            int cell = idx >> 7;
            int c4   = idx & (C4 - 1);
            int ry   = cell / SX;
            int rx   = cell - ry * SX;
            int gy   = min(by0 + ry, FH - 1);   // edge bins: duplicate last row/col
            int gx   = min(bx0 + rx, FW - 1);
            __builtin_amdgcn_global_load_lds(
                (const GLOBAL_AS void*)(in4 + (size_t)((r * FH + gy) * FW + gx) * C4 + c4),
                (LDS_AS void*)&lds[idx], 16, 0, 0);
        }
    }
    // Stage point metadata (overlaps with async tile staging).
    if (tid < cnt) {
        pmS[tid] = perm[base + tid];
        xyS[tid] = sXY[base + tid];
    }
    __syncthreads();   // drains vmcnt(0): global_load_lds writes are visible

    int g  = tid >> 7;            // 4 groups of 128 threads
    int c4 = tid & (C4 - 1);
    f32x4* out4 = (f32x4*)out;

    int i = g;
    // 2-point unrolled loop per group: 8 LDS reads in flight.
    for (; i + 4 < cnt; i += 8) {
        int    ptA = pmS[i];
        float2 cA  = xyS[i];
        int    ptB = pmS[i + 4];
        float2 cB  = xyS[i + 4];

        int x0A, x1A, y0A, y1A, x0B, x1B, y0B, y1B;
        float waA, wbA, wcA, wdA, waB, wbB, wcB, wdB;
        weights_and_cells(cA.x, cA.y, x0A, x1A, y0A, y1A, waA, wbA, wcA, wdA);
        weights_and_cells(cB.x, cB.y, x0B, x1B, y0B, y1B, waB, wbB, wcB, wdB);

        f32x4 Aa = lds[(((y0A - by0) * SX + (x0A - bx0)) << 7) + c4];
        f32x4 Ab = lds[(((y1A - by0) * SX + (x0A - bx0)) << 7) + c4];
        f32x4 Ac = lds[(((y0A - by0) * SX + (x1A - bx0)) << 7) + c4];
        f32x4 Ad = lds[(((y1A - by0) * SX + (x1A - bx0)) << 7) + c4];
        f32x4 Ba = lds[(((y0B - by0) * SX + (x0B - bx0)) << 7) + c4];
        f32x4 Bb = lds[(((y1B - by0) * SX + (x0B - bx0)) << 7) + c4];
        f32x4 Bc = lds[(((y0B - by0) * SX + (x1B - bx0)) << 7) + c4];
        f32x4 Bd = lds[(((y1B - by0) * SX + (x1B - bx0)) << 7) + c4];

        __builtin_nontemporal_store(lerp4(Aa, Ab, Ac, Ad, waA, wbA, wcA, wdA),
                                    out4 + (size_t)ptA * C4 + c4);
        __builtin_nontemporal_store(lerp4(Ba, Bb, Bc, Bd, waB, wbB, wcB, wdB),
                                    out4 + (size_t)ptB * C4 + c4);
    }
    if (i < cnt) {
        int    pt = pmS[i];
        float2 cc = xyS[i];
        int x0, x1, y0, y1; float wa, wb, wc, wd;
        weights_and_cells(cc.x, cc.y, x0, x1, y0, y1, wa, wb, wc, wd);
        f32x4 A = lds[(((y0 - by0) * SX + (x0 - bx0)) << 7) + c4];
        f32x4 B = lds[(((y1 - by0) * SX + (x0 - bx0)) << 7) + c4];
        f32x4 C = lds[(((y0 - by0) * SX + (x1 - bx0)) << 7) + c4];
        f32x4 D = lds[(((y1 - by0) * SX + (x1 - bx0)) << 7) + c4];
        __builtin_nontemporal_store(lerp4(A, B, C, D, wa, wb, wc, wd),
                                    out4 + (size_t)pt * C4 + c4);
    }

    // Cold path: overflow points (slot >= CAP) via direct global gather.
    int ov = min(*ovCnt, OVCAP);
    for (int j = b; j < ov; j += NBINS) {
        if (g != 0) continue;
        int pt = ovList[j];
        int rr = pt / NV;
        float x = fminf(fmaxf(imx[pt], 0.0f), (float)(FW - 1));
        float y = fminf(fmaxf(imy[pt], 0.0f), (float)(FH - 1));
        int x0, x1, y0, y1; float wa, wb, wc, wd;
        weights_and_cells(x, y, x0, x1, y0, y1, wa, wb, wc, wd);
        int rb = rr * FH;
        f32x4 A = in4[(size_t)((rb + y0) * FW + x0) * C4 + c4];
        f32x4 B = in4[(size_t)((rb + y1) * FW + x0) * C4 + c4];
        f32x4 C = in4[(size_t)((rb + y0) * FW + x1) * C4 + c4];
        f32x4 D = in4[(size_t)((rb + y1) * FW + x1) * C4 + c4];
        __builtin_nontemporal_store(lerp4(A, B, C, D, wa, wb, wc, wd),
                                    out4 + (size_t)pt * C4 + c4);
    }
}

// Fallback (workspace too small): unsorted direct kernel.
__global__ __launch_bounds__(256) void st_bilinear_direct(
    const float* __restrict__ inp,
    const float* __restrict__ imx,
    const float* __restrict__ imy,
    float* __restrict__ out)
{
    int gid = blockIdx.x * blockDim.x + threadIdx.x;
    int pt = gid >> 7;
    int c4 = gid & (C4 - 1);
    if (pt >= NPTS) return;
    int r = pt / NV;
    float x = fminf(fmaxf(imx[pt], 0.0f), (float)(FW - 1));
    float y = fminf(fmaxf(imy[pt], 0.0f), (float)(FH - 1));
    int x0, x1, y0, y1; float wa, wb, wc, wd;
    weights_and_cells(x, y, x0, x1, y0, y1, wa, wb, wc, wd);
    const f32x4* base = (const f32x4*)inp;
    int rb = r * FH;
    f32x4 a = base[(size_t)((rb + y0) * FW + x0) * C4 + c4];
    f32x4 b = base[(size_t)((rb + y1) * FW + x0) * C4 + c4];
    f32x4 c = base[(size_t)((rb + y0) * FW + x1) * C4 + c4];
    f32x4 d = base[(size_t)((rb + y1) * FW + x1) * C4 + c4];
    ((f32x4*)out)[(size_t)pt * C4 + c4] = lerp4(a, b, c, d, wa, wb, wc, wd);
}

extern "C" void kernel_launch(void* const* d_in, const int* in_sizes, int n_in,
                              void* d_out, int out_size, void* d_ws, size_t ws_size,
                              hipStream_t stream) {
    const float* inp = (const float*)d_in[0];
    const float* imx = (const float*)d_in[1];
    const float* imy = (const float*)d_in[2];
    float* out = (float*)d_out;

    // ws: binCnt[NBINS] | ovCnt[1] | perm[NBINS*CAP] | sXY[NBINS*CAP] float2 | ovList
    size_t need = (size_t)(NBINS + 1 + NBINS * CAP + OVCAP) * sizeof(int)
                + (size_t)NBINS * CAP * sizeof(float2);   // ~2.25 MB

    if (ws_size < need) {
        int nblocks = (NPTS * C4) / 256;
        hipLaunchKernelGGL(st_bilinear_direct, dim3(nblocks), dim3(256), 0, stream,
                           inp, imx, imy, out);
        return;
    }

    int*    binCnt = (int*)d_ws;
    int*    ovCnt  = binCnt + NBINS;
    int*    perm   = ovCnt + 1;
    float2* sXY    = (float2*)(perm + (size_t)NBINS * CAP);
    int*    ovList = (int*)(sXY + (size_t)NBINS * CAP);

    (void)hipMemsetAsync(binCnt, 0, (NBINS + 1) * sizeof(int), stream);
    hipLaunchKernelGGL(k_scatter, dim3((NPTS + 255) / 256), dim3(256), 0, stream,
                       imx, imy, binCnt, ovCnt, perm, sXY, ovList);
    hipLaunchKernelGGL(st_bins, dim3(NBINS), dim3(TPB), 0, stream,
                       inp, binCnt, ovCnt, perm, sXY, ovList, imx, imy, out);
}